// Round 2
// baseline (1063.807 us; speedup 1.0000x reference)
//
#include <hip/hip_runtime.h>
#include <hip/hip_bf16.h>

// Problem constants (B=2, N=2048, DIM=1024, H=16, HD=64, BS=64, M=32)
#define BB 2
#define NN 2048
#define DIMD 1024
#define HH 16
#define HD64 64
#define MB 32
#define SCALE_F 0.125f   // HD^-0.5

// ---------------------------------------------------------------------------
// QKV GEMM: C[r][j] = sum_d x[r][d] * qkv_w[j][d],  r in [0,4096), j in [0,3072)
// Scatter into q/k/v fp32 [B][H][N][HD] layouts.
// 64x64 tile, BK=32, 256 threads, 4x4 micro-tile per thread.
// ---------------------------------------------------------------------------
__global__ __launch_bounds__(256) void qkv_gemm_kernel(
    const float* __restrict__ x, const float* __restrict__ w,
    float* __restrict__ qf, float* __restrict__ kf, float* __restrict__ vf)
{
    __shared__ float As[64][33];
    __shared__ float Bs[64][33];
    const int tid = threadIdx.x;
    const int row0 = blockIdx.y * 64;       // token-row tile
    const int col0 = blockIdx.x * 64;       // output-col tile (within one t,h)
    const int ty = tid >> 4, tx = tid & 15;

    float acc[4][4] = {};
    for (int k0 = 0; k0 < 1024; k0 += 32) {
        #pragma unroll
        for (int i = 0; i < 8; ++i) {
            int e = tid + i * 256;
            int r = e >> 5, c = e & 31;
            As[r][c] = x[(size_t)(row0 + r) * 1024 + k0 + c];
            Bs[r][c] = w[(size_t)(col0 + r) * 1024 + k0 + c];
        }
        __syncthreads();
        #pragma unroll
        for (int kk = 0; kk < 32; ++kk) {
            float a[4], b[4];
            #pragma unroll
            for (int i = 0; i < 4; ++i) a[i] = As[ty * 4 + i][kk];
            #pragma unroll
            for (int j = 0; j < 4; ++j) b[j] = Bs[tx * 4 + j][kk];
            #pragma unroll
            for (int i = 0; i < 4; ++i)
                #pragma unroll
                for (int j = 0; j < 4; ++j)
                    acc[i][j] += a[i] * b[j];
        }
        __syncthreads();
    }

    // Scatter: whole 64-col tile lies inside one (t, h) since col0 % 64 == 0.
    const int tsel = col0 >> 10;                 // 0=q, 1=k, 2=v
    const int h    = (col0 & 1023) >> 6;
    float* dstbuf = (tsel == 0) ? qf : (tsel == 1) ? kf : vf;
    #pragma unroll
    for (int i = 0; i < 4; ++i) {
        int row = row0 + ty * 4 + i;
        int b   = row >> 11, n = row & 2047;
        size_t rb = ((size_t)(b * HH + h) * NN + n) * HD64;
        #pragma unroll
        for (int j = 0; j < 4; ++j)
            dstbuf[rb + tx * 4 + j] = acc[i][j];
    }
}

// ---------------------------------------------------------------------------
// Block means: qb/kb [B][H][M][HD] = mean over 64 tokens of each block.
// 131072 total outputs (q then k).
// ---------------------------------------------------------------------------
__global__ __launch_bounds__(256) void block_mean_kernel(
    const float* __restrict__ qf, const float* __restrict__ kf,
    float* __restrict__ qbf, float* __restrict__ kbf)
{
    int idx = blockIdx.x * 256 + threadIdx.x;   // 0..131071
    const float* src = (idx < 65536) ? qf : kf;
    float* dst       = (idx < 65536) ? qbf : kbf;
    int e = idx & 65535;
    int d = e & 63;
    int r = e >> 6;                              // bh*32 + m
    size_t base = (size_t)r * 4096 + d;          // (r*64 + 0)*64 + d
    float s = 0.f;
    #pragma unroll
    for (int i = 0; i < 64; ++i) s += src[base + (size_t)i * 64];
    dst[e] = s * (1.f / 64.f);
}

// ---------------------------------------------------------------------------
// Block scores + top-2 threshold + diagonal -> 32-bit keep mask per (bh, m).
// One block per bh (32 blocks), 128 threads.
// ---------------------------------------------------------------------------
__global__ __launch_bounds__(128) void block_scores_kernel(
    const float* __restrict__ qbf, const float* __restrict__ kbf,
    unsigned int* __restrict__ maskbits)
{
    __shared__ float qs[32][64];
    __shared__ float ks[32][64];
    __shared__ float cb[32][32];
    const int bh = blockIdx.x;
    const int tid = threadIdx.x;

    #pragma unroll
    for (int i = 0; i < 16; ++i) {
        int e = tid + i * 128;
        qs[e >> 6][e & 63] = qbf[(size_t)bh * 2048 + e];
        ks[e >> 6][e & 63] = kbf[(size_t)bh * 2048 + e];
    }
    __syncthreads();

    #pragma unroll
    for (int i = 0; i < 8; ++i) {
        int idx = tid + i * 128;
        int r = idx >> 5, c = idx & 31;
        float s = 0.f;
        #pragma unroll
        for (int d = 0; d < 64; ++d) s += qs[r][d] * ks[c][d];
        cb[r][c] = s * SCALE_F;
    }
    __syncthreads();

    if (tid < 32) {
        // top-2 values (thresh = 2nd largest, duplicates allowed, matches top_k)
        float m1 = -INFINITY, m2 = -INFINITY;
        for (int n = 0; n < 32; ++n) {
            float v = cb[tid][n];
            if (v > m1) { m2 = m1; m1 = v; }
            else if (v > m2) { m2 = v; }
        }
        unsigned int bits = 1u << tid;           // diagonal always kept
        for (int n = 0; n < 32; ++n)
            if (cb[tid][n] >= m2) bits |= 1u << n;
        maskbits[bh * 32 + tid] = bits;
    }
}

// ---------------------------------------------------------------------------
// Sparse block attention with online softmax.
// One block per (bh, m): 1024 blocks x 64 threads; thread = one query row.
// Writes attn in [B][N][DIM] layout (head-interleaved) for the proj GEMM.
// ---------------------------------------------------------------------------
__global__ __launch_bounds__(64) void sparse_attn_kernel(
    const float* __restrict__ qf, const float* __restrict__ kf,
    const float* __restrict__ vf, const unsigned int* __restrict__ maskbits,
    float* __restrict__ attnf)
{
    __shared__ float kbuf[64][64];
    __shared__ float vbuf[64][64];
    __shared__ float sbuf[64][65];   // +1 pad: avoid 64-float-stride bank conflict
    const int m  = blockIdx.x & 31;
    const int bh = blockIdx.x >> 5;
    const int b  = bh >> 4, h = bh & 15;
    const int t  = threadIdx.x;      // query row within block

    float qreg[64];
    size_t qrow = ((size_t)bh * NN + m * 64 + t) * HD64;
    #pragma unroll
    for (int d = 0; d < 64; ++d) qreg[d] = qf[qrow + d];

    const unsigned int mask = maskbits[bh * 32 + m];
    float macc = -INFINITY, lacc = 0.f;
    float oacc[64];
    #pragma unroll
    for (int d = 0; d < 64; ++d) oacc[d] = 0.f;

    for (int nb = 0; nb < 32; ++nb) {
        if (!((mask >> nb) & 1u)) continue;      // uniform across block
        __syncthreads();
        size_t kb0 = ((size_t)bh * NN + nb * 64) * HD64;
        for (int i = 0; i < 64; ++i) {           // coalesced: lane t -> consecutive
            kbuf[i][t] = kf[kb0 + (size_t)i * 64 + t];
            vbuf[i][t] = vf[kb0 + (size_t)i * 64 + t];
        }
        __syncthreads();

        float bmax = -INFINITY;
        for (int kk = 0; kk < 64; ++kk) {
            float s = 0.f;
            #pragma unroll
            for (int d = 0; d < 64; ++d) s += qreg[d] * kbuf[kk][d];
            s *= SCALE_F;
            sbuf[t][kk] = s;
            bmax = fmaxf(bmax, s);
        }
        float mnew  = fmaxf(macc, bmax);
        float alpha = expf(macc - mnew);         // macc=-inf -> alpha=0, no NaN
        lacc *= alpha;
        #pragma unroll
        for (int d = 0; d < 64; ++d) oacc[d] *= alpha;
        for (int kk = 0; kk < 64; ++kk) {
            float p = expf(sbuf[t][kk] - mnew);
            lacc += p;
            #pragma unroll
            for (int d = 0; d < 64; ++d) oacc[d] += p * vbuf[kk][d];
        }
        macc = mnew;
    }

    float inv = (lacc > 0.f) ? (1.f / lacc) : 0.f;   // guard: no 0*inf path
    size_t orow = ((size_t)b * NN + m * 64 + t) * DIMD + h * 64;
    #pragma unroll
    for (int d = 0; d < 64; ++d) attnf[orow + d] = oacc[d] * inv;
}

// ---------------------------------------------------------------------------
// Output projection: out[r][c] = sum_d attn[r][d] * proj_w[c][d] + proj_b[c]
// fp32 in/out. Same tiling as qkv GEMM.
// ---------------------------------------------------------------------------
__global__ __launch_bounds__(256) void proj_gemm_kernel(
    const float* __restrict__ attn, const float* __restrict__ w,
    const float* __restrict__ bias, float* __restrict__ out)
{
    __shared__ float As[64][33];
    __shared__ float Bs[64][33];
    const int tid = threadIdx.x;
    const int row0 = blockIdx.y * 64;
    const int col0 = blockIdx.x * 64;
    const int ty = tid >> 4, tx = tid & 15;

    float acc[4][4] = {};
    for (int k0 = 0; k0 < 1024; k0 += 32) {
        #pragma unroll
        for (int i = 0; i < 8; ++i) {
            int e = tid + i * 256;
            int r = e >> 5, c = e & 31;
            As[r][c] = attn[(size_t)(row0 + r) * 1024 + k0 + c];
            Bs[r][c] = w[(size_t)(col0 + r) * 1024 + k0 + c];
        }
        __syncthreads();
        #pragma unroll
        for (int kk = 0; kk < 32; ++kk) {
            float a[4], b[4];
            #pragma unroll
            for (int i = 0; i < 4; ++i) a[i] = As[ty * 4 + i][kk];
            #pragma unroll
            for (int j = 0; j < 4; ++j) b[j] = Bs[tx * 4 + j][kk];
            #pragma unroll
            for (int i = 0; i < 4; ++i)
                #pragma unroll
                for (int j = 0; j < 4; ++j)
                    acc[i][j] += a[i] * b[j];
        }
        __syncthreads();
    }

    #pragma unroll
    for (int j = 0; j < 4; ++j) {
        int col = col0 + tx * 4 + j;
        float bv = bias[col];
        #pragma unroll
        for (int i = 0; i < 4; ++i) {
            int row = row0 + ty * 4 + i;
            out[(size_t)row * 1024 + col] = acc[i][j] + bv;
        }
    }
}

// ---------------------------------------------------------------------------
extern "C" void kernel_launch(void* const* d_in, const int* in_sizes, int n_in,
                              void* d_out, int out_size, void* d_ws, size_t ws_size,
                              hipStream_t stream)
{
    const float* x      = (const float*)d_in[0];
    const float* qkv_w  = (const float*)d_in[1];
    const float* proj_w = (const float*)d_in[2];
    const float* proj_b = (const float*)d_in[3];
    float* out = (float*)d_out;

    // Workspace carve (fp32): q,k,v,attn 4x 4194304 + qb,kb 2x 65536 + mask
    float* qf    = (float*)d_ws;
    float* kf    = qf + 4194304;
    float* vf    = kf + 4194304;
    float* attnf = vf + 4194304;
    float* qbf   = attnf + 4194304;
    float* kbf   = qbf + 65536;
    unsigned int* maskb = (unsigned int*)(kbf + 65536);

    qkv_gemm_kernel<<<dim3(48, 64), 256, 0, stream>>>(x, qkv_w, qf, kf, vf);
    block_mean_kernel<<<512, 256, 0, stream>>>(qf, kf, qbf, kbf);
    block_scores_kernel<<<32, 128, 0, stream>>>(qbf, kbf, maskb);
    sparse_attn_kernel<<<1024, 64, 0, stream>>>(qf, kf, vf, maskb, attnf);
    proj_gemm_kernel<<<dim3(16, 64), 256, 0, stream>>>(attnf, proj_w, proj_b, out);
}

// Round 4
// 528.979 us; speedup vs baseline: 2.0111x; 2.0111x over previous
//
#include <hip/hip_runtime.h>
#include <hip/hip_bf16.h>

// Problem constants (B=2, N=2048, DIM=1024, H=16, HD=64, BS=64, M=32)
#define BB 2
#define NN 2048
#define DIMD 1024
#define HH 16
#define HD64 64
#define MB 32
#define SCALE_F 0.125f   // HD^-0.5

typedef __attribute__((ext_vector_type(8))) short bf16x8;
typedef __attribute__((ext_vector_type(4))) float f32x4;

__device__ __forceinline__ unsigned short bf16_hi(float f) {
    return __builtin_bit_cast(unsigned short, __float2bfloat16(f));
}
__device__ __forceinline__ float bf16_val(unsigned short u) {
    return __bfloat162float(__builtin_bit_cast(__hip_bfloat16, u));
}
__device__ __forceinline__ void async_copy16(const void* g, void* l) {
    __builtin_amdgcn_global_load_lds((const __attribute__((address_space(1))) void*)g,
                                     (__attribute__((address_space(3))) void*)l, 16, 0, 0);
}

// ===========================================================================
// FAST PATH (bf16x3 MFMA emulation of fp32 GEMMs)
// ===========================================================================

// Split fp32 [rows][1024] -> bf16 hi|lo [rows][2048] (hi at col, lo at col+1024)
__global__ __launch_bounds__(256) void split_bf16_kernel(
    const float* __restrict__ src, short* __restrict__ dst, int total4)
{
    int idx = blockIdx.x * 256 + threadIdx.x;
    if (idx >= total4) return;
    int e = idx * 4;
    int r = e >> 10, c = e & 1023;
    float4 v = *(const float4*)(src + e);
    unsigned short h0 = bf16_hi(v.x), h1 = bf16_hi(v.y), h2 = bf16_hi(v.z), h3 = bf16_hi(v.w);
    unsigned short l0 = bf16_hi(v.x - bf16_val(h0));
    unsigned short l1 = bf16_hi(v.y - bf16_val(h1));
    unsigned short l2 = bf16_hi(v.z - bf16_val(h2));
    unsigned short l3 = bf16_hi(v.w - bf16_val(h3));
    size_t base = (size_t)r * 2048 + c;
    *(ushort4*)(dst + base)        = make_ushort4(h0, h1, h2, h3);
    *(ushort4*)(dst + base + 1024) = make_ushort4(l0, l1, l2, l3);
}

// QKV GEMM via bf16x3 MFMA. A:[4096][2048] hi|lo, W:[3072][2048] hi|lo.
// Virtual K=3072: seg0 hiA*hiW, seg1 hiA*loW, seg2 loA*hiW.
// 128x128 tile, BK=32, 256 threads (4 waves, 2x2 of 64x64 per wave).
__global__ __launch_bounds__(256) void qkv_mfma_kernel(
    const short* __restrict__ A, const short* __restrict__ W,
    float* __restrict__ qf, float* __restrict__ kf, float* __restrict__ vf)
{
    __shared__ short As[128 * 32];
    __shared__ short Bs[128 * 32];
    const int tid = threadIdx.x;
    const int lane = tid & 63;
    const int wave = tid >> 6;
    const int row0 = blockIdx.y * 128;
    const int col0 = blockIdx.x * 128;
    const int wm = wave & 1, wn = wave >> 1;

    f32x4 acc[4][4];
    const f32x4 zero = {0.f, 0.f, 0.f, 0.f};
    #pragma unroll
    for (int i = 0; i < 4; ++i)
        #pragma unroll
        for (int j = 0; j < 4; ++j) acc[i][j] = zero;

    const int ldr = lane >> 2;           // 0..15
    const int lko = (lane & 3) * 8;      // 0,8,16,24

    for (int kt = 0; kt < 96; ++kt) {
        const int seg = kt >> 5;
        const int kk = (kt & 31) << 5;
        const int ka0 = kk + (seg == 2 ? 1024 : 0);
        const int kw0 = kk + (seg == 1 ? 1024 : 0);
        #pragma unroll
        for (int i = 0; i < 2; ++i) {
            const int chunk = wave * 2 + i;          // 0..7 (16 rows each)
            const short* gA = A + (size_t)(row0 + chunk * 16 + ldr) * 2048 + ka0 + lko;
            const short* gB = W + (size_t)(col0 + chunk * 16 + ldr) * 2048 + kw0 + lko;
            async_copy16(gA, (char*)As + chunk * 1024);
            async_copy16(gB, (char*)Bs + chunk * 1024);
        }
        __syncthreads();
        bf16x8 af[4], bfr[4];
        #pragma unroll
        for (int mi = 0; mi < 4; ++mi)
            af[mi] = *(const bf16x8*)(As + (wm * 64 + mi * 16 + (lane & 15)) * 32 + (lane >> 4) * 8);
        #pragma unroll
        for (int ni = 0; ni < 4; ++ni)
            bfr[ni] = *(const bf16x8*)(Bs + (wn * 64 + ni * 16 + (lane & 15)) * 32 + (lane >> 4) * 8);
        #pragma unroll
        for (int mi = 0; mi < 4; ++mi)
            #pragma unroll
            for (int ni = 0; ni < 4; ++ni)
                acc[mi][ni] = __builtin_amdgcn_mfma_f32_16x16x32_bf16(af[mi], bfr[ni], acc[mi][ni], 0, 0, 0);
        __syncthreads();
    }

    // epilogue: scatter into q/k/v [B][H][N][HD]
    #pragma unroll
    for (int ni = 0; ni < 4; ++ni) {
        int gc = col0 + wn * 64 + ni * 16 + (lane & 15);   // 0..3071
        int tsel = gc >> 10;
        int h = (gc >> 6) & 15;
        int d = gc & 63;
        float* dst = (tsel == 0) ? qf : (tsel == 1) ? kf : vf;
        #pragma unroll
        for (int mi = 0; mi < 4; ++mi) {
            int gr0 = row0 + wm * 64 + mi * 16 + (lane >> 4) * 4;
            #pragma unroll
            for (int r = 0; r < 4; ++r) {
                int gr = gr0 + r;
                int b = gr >> 11, n = gr & 2047;
                dst[(((size_t)((b << 4) + h)) * NN + n) * HD64 + d] = acc[mi][ni][r];
            }
        }
    }
}

// Proj GEMM via bf16x3 MFMA + bias. A:[4096][2048] hi|lo, W:[1024][2048] hi|lo.
// 128(M)x64(N) tile, 4 waves each 32x64 (2x4 MFMA tiles).
__global__ __launch_bounds__(256) void proj_mfma_kernel(
    const short* __restrict__ A, const short* __restrict__ W,
    const float* __restrict__ bias, float* __restrict__ out)
{
    __shared__ short As[128 * 32];
    __shared__ short Bs[64 * 32];
    const int tid = threadIdx.x;
    const int lane = tid & 63;
    const int wave = tid >> 6;
    const int row0 = blockIdx.y * 128;
    const int col0 = blockIdx.x * 64;

    f32x4 acc[2][4];
    const f32x4 zero = {0.f, 0.f, 0.f, 0.f};
    #pragma unroll
    for (int i = 0; i < 2; ++i)
        #pragma unroll
        for (int j = 0; j < 4; ++j) acc[i][j] = zero;

    const int ldr = lane >> 2;
    const int lko = (lane & 3) * 8;

    for (int kt = 0; kt < 96; ++kt) {
        const int seg = kt >> 5;
        const int kk = (kt & 31) << 5;
        const int ka0 = kk + (seg == 2 ? 1024 : 0);
        const int kw0 = kk + (seg == 1 ? 1024 : 0);
        #pragma unroll
        for (int i = 0; i < 2; ++i) {
            const int chunk = wave * 2 + i;
            const short* gA = A + (size_t)(row0 + chunk * 16 + ldr) * 2048 + ka0 + lko;
            async_copy16(gA, (char*)As + chunk * 1024);
        }
        {
            const short* gB = W + (size_t)(col0 + wave * 16 + ldr) * 2048 + kw0 + lko;
            async_copy16(gB, (char*)Bs + wave * 1024);
        }
        __syncthreads();
        bf16x8 af[2], bfr[4];
        #pragma unroll
        for (int mi = 0; mi < 2; ++mi)
            af[mi] = *(const bf16x8*)(As + (wave * 32 + mi * 16 + (lane & 15)) * 32 + (lane >> 4) * 8);
        #pragma unroll
        for (int ni = 0; ni < 4; ++ni)
            bfr[ni] = *(const bf16x8*)(Bs + (ni * 16 + (lane & 15)) * 32 + (lane >> 4) * 8);
        #pragma unroll
        for (int mi = 0; mi < 2; ++mi)
            #pragma unroll
            for (int ni = 0; ni < 4; ++ni)
                acc[mi][ni] = __builtin_amdgcn_mfma_f32_16x16x32_bf16(af[mi], bfr[ni], acc[mi][ni], 0, 0, 0);
        __syncthreads();
    }

    #pragma unroll
    for (int ni = 0; ni < 4; ++ni) {
        int gc = col0 + ni * 16 + (lane & 15);
        float bv = bias[gc];
        #pragma unroll
        for (int mi = 0; mi < 2; ++mi) {
            int gr0 = row0 + wave * 32 + mi * 16 + (lane >> 4) * 4;
            #pragma unroll
            for (int r = 0; r < 4; ++r)
                out[(size_t)(gr0 + r) * 1024 + gc] = acc[mi][ni][r] + bv;
        }
    }
}

// ===========================================================================
// FALLBACK PATH (HW-proven round-2 fp32 GEMMs) — used if ws_size is too small
// ===========================================================================

__global__ __launch_bounds__(256) void qkv_gemm_fb(
    const float* __restrict__ x, const float* __restrict__ w,
    float* __restrict__ qf, float* __restrict__ kf, float* __restrict__ vf)
{
    __shared__ float As[64][33];
    __shared__ float Bs[64][33];
    const int tid = threadIdx.x;
    const int row0 = blockIdx.y * 64;
    const int col0 = blockIdx.x * 64;
    const int ty = tid >> 4, tx = tid & 15;

    float acc[4][4] = {};
    for (int k0 = 0; k0 < 1024; k0 += 32) {
        #pragma unroll
        for (int i = 0; i < 8; ++i) {
            int e = tid + i * 256;
            int r = e >> 5, c = e & 31;
            As[r][c] = x[(size_t)(row0 + r) * 1024 + k0 + c];
            Bs[r][c] = w[(size_t)(col0 + r) * 1024 + k0 + c];
        }
        __syncthreads();
        #pragma unroll
        for (int kk = 0; kk < 32; ++kk) {
            float a[4], b[4];
            #pragma unroll
            for (int i = 0; i < 4; ++i) a[i] = As[ty * 4 + i][kk];
            #pragma unroll
            for (int j = 0; j < 4; ++j) b[j] = Bs[tx * 4 + j][kk];
            #pragma unroll
            for (int i = 0; i < 4; ++i)
                #pragma unroll
                for (int j = 0; j < 4; ++j)
                    acc[i][j] += a[i] * b[j];
        }
        __syncthreads();
    }

    const int tsel = col0 >> 10;
    const int h    = (col0 & 1023) >> 6;
    float* dstbuf = (tsel == 0) ? qf : (tsel == 1) ? kf : vf;
    #pragma unroll
    for (int i = 0; i < 4; ++i) {
        int row = row0 + ty * 4 + i;
        int b   = row >> 11, n = row & 2047;
        size_t rb = ((size_t)(b * HH + h) * NN + n) * HD64;
        #pragma unroll
        for (int j = 0; j < 4; ++j)
            dstbuf[rb + tx * 4 + j] = acc[i][j];
    }
}

__global__ __launch_bounds__(256) void proj_gemm_fb(
    const float* __restrict__ attn, const float* __restrict__ w,
    const float* __restrict__ bias, float* __restrict__ out)
{
    __shared__ float As[64][33];
    __shared__ float Bs[64][33];
    const int tid = threadIdx.x;
    const int row0 = blockIdx.y * 64;
    const int col0 = blockIdx.x * 64;
    const int ty = tid >> 4, tx = tid & 15;

    float acc[4][4] = {};
    for (int k0 = 0; k0 < 1024; k0 += 32) {
        #pragma unroll
        for (int i = 0; i < 8; ++i) {
            int e = tid + i * 256;
            int r = e >> 5, c = e & 31;
            As[r][c] = attn[(size_t)(row0 + r) * 1024 + k0 + c];
            Bs[r][c] = w[(size_t)(col0 + r) * 1024 + k0 + c];
        }
        __syncthreads();
        #pragma unroll
        for (int kk = 0; kk < 32; ++kk) {
            float a[4], b[4];
            #pragma unroll
            for (int i = 0; i < 4; ++i) a[i] = As[ty * 4 + i][kk];
            #pragma unroll
            for (int j = 0; j < 4; ++j) b[j] = Bs[tx * 4 + j][kk];
            #pragma unroll
            for (int i = 0; i < 4; ++i)
                #pragma unroll
                for (int j = 0; j < 4; ++j)
                    acc[i][j] += a[i] * b[j];
        }
        __syncthreads();
    }

    #pragma unroll
    for (int j = 0; j < 4; ++j) {
        int col = col0 + tx * 4 + j;
        float bv = bias[col];
        #pragma unroll
        for (int i = 0; i < 4; ++i) {
            int row = row0 + ty * 4 + i;
            out[(size_t)row * 1024 + col] = acc[i][j] + bv;
        }
    }
}

// ===========================================================================
// SHARED KERNELS
// ===========================================================================

__global__ __launch_bounds__(256) void block_mean_kernel(
    const float* __restrict__ qf, const float* __restrict__ kf,
    float* __restrict__ qbf, float* __restrict__ kbf)
{
    int idx = blockIdx.x * 256 + threadIdx.x;   // 0..131071
    const float* src = (idx < 65536) ? qf : kf;
    float* dst       = (idx < 65536) ? qbf : kbf;
    int e = idx & 65535;
    int d = e & 63;
    int r = e >> 6;                              // bh*32 + m
    size_t base = (size_t)r * 4096 + d;
    float s = 0.f;
    #pragma unroll
    for (int i = 0; i < 64; ++i) s += src[base + (size_t)i * 64];
    dst[e] = s * (1.f / 64.f);
}

__global__ __launch_bounds__(128) void block_scores_kernel(
    const float* __restrict__ qbf, const float* __restrict__ kbf,
    unsigned int* __restrict__ maskbits)
{
    __shared__ float qs[32][64];
    __shared__ float ks[32][64];
    __shared__ float cb[32][32];
    const int bh = blockIdx.x;
    const int tid = threadIdx.x;

    #pragma unroll
    for (int i = 0; i < 16; ++i) {
        int e = tid + i * 128;
        qs[e >> 6][e & 63] = qbf[(size_t)bh * 2048 + e];
        ks[e >> 6][e & 63] = kbf[(size_t)bh * 2048 + e];
    }
    __syncthreads();

    #pragma unroll
    for (int i = 0; i < 8; ++i) {
        int idx = tid + i * 128;
        int r = idx >> 5, c = idx & 31;
        float s = 0.f;
        #pragma unroll
        for (int d = 0; d < 64; ++d) s += qs[r][d] * ks[c][d];
        cb[r][c] = s * SCALE_F;
    }
    __syncthreads();

    if (tid < 32) {
        float m1 = -INFINITY, m2 = -INFINITY;
        for (int n = 0; n < 32; ++n) {
            float v = cb[tid][n];
            if (v > m1) { m2 = m1; m1 = v; }
            else if (v > m2) { m2 = v; }
        }
        unsigned int bits = 1u << tid;
        for (int n = 0; n < 32; ++n)
            if (cb[tid][n] >= m2) bits |= 1u << n;
        maskbits[bh * 32 + tid] = bits;
    }
}

// Sparse block attention with online softmax. One block per (bh, m), 64 thr.
// split_out=1: write bf16 hi|lo [4096][2048] to aout; else fp32 [B][N][DIM] to attnf.
__global__ __launch_bounds__(64) void sparse_attn_kernel(
    const float* __restrict__ qf, const float* __restrict__ kf,
    const float* __restrict__ vf, const unsigned int* __restrict__ maskbits,
    short* __restrict__ aout, float* __restrict__ attnf, int split_out)
{
    __shared__ float kbuf[64][64];
    __shared__ float vbuf[64][64];
    __shared__ float sbuf[64][65];
    const int m  = blockIdx.x & 31;
    const int bh = blockIdx.x >> 5;
    const int b  = bh >> 4, h = bh & 15;
    const int t  = threadIdx.x;

    float qreg[64];
    size_t qrow = ((size_t)bh * NN + m * 64 + t) * HD64;
    #pragma unroll
    for (int d = 0; d < 64; ++d) qreg[d] = qf[qrow + d];

    const unsigned int mask = maskbits[bh * 32 + m];
    float macc = -INFINITY, lacc = 0.f;
    float oacc[64];
    #pragma unroll
    for (int d = 0; d < 64; ++d) oacc[d] = 0.f;

    for (int nb = 0; nb < 32; ++nb) {
        if (!((mask >> nb) & 1u)) continue;      // uniform across block
        __syncthreads();
        size_t kb0 = ((size_t)bh * NN + nb * 64) * HD64;
        for (int i = 0; i < 64; ++i) {
            kbuf[i][t] = kf[kb0 + (size_t)i * 64 + t];
            vbuf[i][t] = vf[kb0 + (size_t)i * 64 + t];
        }
        __syncthreads();

        float bmax = -INFINITY;
        for (int kk = 0; kk < 64; ++kk) {
            float s = 0.f;
            #pragma unroll
            for (int d = 0; d < 64; ++d) s += qreg[d] * kbuf[kk][d];
            s *= SCALE_F;
            sbuf[t][kk] = s;
            bmax = fmaxf(bmax, s);
        }
        float mnew  = fmaxf(macc, bmax);
        float alpha = expf(macc - mnew);
        lacc *= alpha;
        #pragma unroll
        for (int d = 0; d < 64; ++d) oacc[d] *= alpha;
        for (int kk = 0; kk < 64; ++kk) {
            float p = expf(sbuf[t][kk] - mnew);
            lacc += p;
            #pragma unroll
            for (int d = 0; d < 64; ++d) oacc[d] += p * vbuf[kk][d];
        }
        macc = mnew;
    }

    float inv = (lacc > 0.f) ? (1.f / lacc) : 0.f;
    if (split_out) {
        size_t orow = ((size_t)(b * NN + m * 64 + t)) * 2048 + h * 64;
        #pragma unroll
        for (int d0 = 0; d0 < 64; d0 += 4) {
            float f0 = oacc[d0] * inv, f1 = oacc[d0 + 1] * inv,
                  f2 = oacc[d0 + 2] * inv, f3 = oacc[d0 + 3] * inv;
            unsigned short h0 = bf16_hi(f0), h1 = bf16_hi(f1), h2 = bf16_hi(f2), h3 = bf16_hi(f3);
            unsigned short l0 = bf16_hi(f0 - bf16_val(h0));
            unsigned short l1 = bf16_hi(f1 - bf16_val(h1));
            unsigned short l2 = bf16_hi(f2 - bf16_val(h2));
            unsigned short l3 = bf16_hi(f3 - bf16_val(h3));
            *(ushort4*)(aout + orow + d0)        = make_ushort4(h0, h1, h2, h3);
            *(ushort4*)(aout + orow + 1024 + d0) = make_ushort4(l0, l1, l2, l3);
        }
    } else {
        size_t orow = ((size_t)(b * NN + m * 64 + t)) * DIMD + h * 64;
        #pragma unroll
        for (int d = 0; d < 64; ++d) attnf[orow + d] = oacc[d] * inv;
    }
}

// ---------------------------------------------------------------------------
extern "C" void kernel_launch(void* const* d_in, const int* in_sizes, int n_in,
                              void* d_out, int out_size, void* d_ws, size_t ws_size,
                              hipStream_t stream)
{
    const float* x      = (const float*)d_in[0];
    const float* qkv_w  = (const float*)d_in[1];
    const float* proj_w = (const float*)d_in[2];
    const float* proj_b = (const float*)d_in[3];
    float* out = (float*)d_out;

    // Common carve (fp32): q,k,v 3x 4194304 + qb,kb 2x 65536 + mask
    float* qf  = (float*)d_ws;
    float* kf  = qf + 4194304;
    float* vf  = kf + 4194304;
    float* qbf = vf + 4194304;
    float* kbf = qbf + 65536;
    unsigned int* maskb = (unsigned int*)(kbf + 65536);

    // Fast-path extra: Axs 4096*2048 bf16 (x split; reused for attn split),
    // Wqs 3072*2048 bf16 (qkv_w split; reused for proj_w split)
    short* Axs = (short*)(maskb + 1024);
    short* Wqs = Axs + (size_t)4096 * 2048;
    const size_t need_fast = (size_t)((char*)(Wqs + (size_t)3072 * 2048) - (char*)d_ws);

    if (ws_size >= need_fast) {
        split_bf16_kernel<<<4096, 256, 0, stream>>>(x, Axs, 1048576);
        split_bf16_kernel<<<3072, 256, 0, stream>>>(qkv_w, Wqs, 786432);
        qkv_mfma_kernel<<<dim3(24, 32), 256, 0, stream>>>(Axs, Wqs, qf, kf, vf);
        block_mean_kernel<<<512, 256, 0, stream>>>(qf, kf, qbf, kbf);
        block_scores_kernel<<<32, 128, 0, stream>>>(qbf, kbf, maskb);
        split_bf16_kernel<<<1024, 256, 0, stream>>>(proj_w, Wqs, 262144);
        sparse_attn_kernel<<<1024, 64, 0, stream>>>(qf, kf, vf, maskb, Axs, (float*)nullptr, 1);
        proj_mfma_kernel<<<dim3(16, 32), 256, 0, stream>>>(Axs, Wqs, proj_b, out);
    } else {
        // Round-2 proven path: attnf fp32 reuses the fast-path split region
        float* attnf = (float*)(maskb + 1024);
        qkv_gemm_fb<<<dim3(48, 64), 256, 0, stream>>>(x, qkv_w, qf, kf, vf);
        block_mean_kernel<<<512, 256, 0, stream>>>(qf, kf, qbf, kbf);
        block_scores_kernel<<<32, 128, 0, stream>>>(qbf, kbf, maskb);
        sparse_attn_kernel<<<1024, 64, 0, stream>>>(qf, kf, vf, maskb, (short*)nullptr, attnf, 0);
        proj_gemm_fb<<<dim3(16, 64), 256, 0, stream>>>(attnf, proj_w, proj_b, out);
    }
}

// Round 5
// 384.579 us; speedup vs baseline: 2.7662x; 1.3755x over previous
//
#include <hip/hip_runtime.h>
#include <hip/hip_bf16.h>

// Problem constants (B=2, N=2048, DIM=1024, H=16, HD=64, BS=64, M=32)
#define BB 2
#define NN 2048
#define DIMD 1024
#define HH 16
#define HD64 64
#define MB 32
#define SCALE_F 0.125f   // HD^-0.5

typedef __attribute__((ext_vector_type(8))) short bf16x8;
typedef __attribute__((ext_vector_type(4))) float f32x4;

__device__ __forceinline__ unsigned short bf16_hi(float f) {
    return __builtin_bit_cast(unsigned short, __float2bfloat16(f));
}
__device__ __forceinline__ float bf16_val(unsigned short u) {
    return __bfloat162float(__builtin_bit_cast(__hip_bfloat16, u));
}
__device__ __forceinline__ void async_copy16(const void* g, void* l) {
    __builtin_amdgcn_global_load_lds((const __attribute__((address_space(1))) void*)g,
                                     (__attribute__((address_space(3))) void*)l, 16, 0, 0);
}

// ===========================================================================
// FAST PATH (bf16x3 MFMA emulation of fp32 GEMMs)
// ===========================================================================

// Split fp32 [rows][1024] -> bf16 hi|lo [rows][2048] (hi at col, lo at col+1024)
__global__ __launch_bounds__(256) void split_bf16_kernel(
    const float* __restrict__ src, short* __restrict__ dst, int total4)
{
    int idx = blockIdx.x * 256 + threadIdx.x;
    if (idx >= total4) return;
    int e = idx * 4;
    int r = e >> 10, c = e & 1023;
    float4 v = *(const float4*)(src + e);
    unsigned short h0 = bf16_hi(v.x), h1 = bf16_hi(v.y), h2 = bf16_hi(v.z), h3 = bf16_hi(v.w);
    unsigned short l0 = bf16_hi(v.x - bf16_val(h0));
    unsigned short l1 = bf16_hi(v.y - bf16_val(h1));
    unsigned short l2 = bf16_hi(v.z - bf16_val(h2));
    unsigned short l3 = bf16_hi(v.w - bf16_val(h3));
    size_t base = (size_t)r * 2048 + c;
    *(ushort4*)(dst + base)        = make_ushort4(h0, h1, h2, h3);
    *(ushort4*)(dst + base + 1024) = make_ushort4(l0, l1, l2, l3);
}

// QKV GEMM via bf16x3 MFMA. A:[4096][2048] hi|lo, W:[3072][2048] hi|lo.
// Virtual K=3072: seg0 hiA*hiW, seg1 hiA*loW, seg2 loA*hiW.
// 128x128 tile, BK=32, 256 threads (4 waves, 2x2 of 64x64 per wave).
__global__ __launch_bounds__(256) void qkv_mfma_kernel(
    const short* __restrict__ A, const short* __restrict__ W,
    float* __restrict__ qf, float* __restrict__ kf, float* __restrict__ vf)
{
    __shared__ short As[128 * 32];
    __shared__ short Bs[128 * 32];
    const int tid = threadIdx.x;
    const int lane = tid & 63;
    const int wave = tid >> 6;
    const int row0 = blockIdx.y * 128;
    const int col0 = blockIdx.x * 128;
    const int wm = wave & 1, wn = wave >> 1;

    f32x4 acc[4][4];
    const f32x4 zero = {0.f, 0.f, 0.f, 0.f};
    #pragma unroll
    for (int i = 0; i < 4; ++i)
        #pragma unroll
        for (int j = 0; j < 4; ++j) acc[i][j] = zero;

    const int ldr = lane >> 2;           // 0..15
    const int lko = (lane & 3) * 8;      // 0,8,16,24

    for (int kt = 0; kt < 96; ++kt) {
        const int seg = kt >> 5;
        const int kk = (kt & 31) << 5;
        const int ka0 = kk + (seg == 2 ? 1024 : 0);
        const int kw0 = kk + (seg == 1 ? 1024 : 0);
        #pragma unroll
        for (int i = 0; i < 2; ++i) {
            const int chunk = wave * 2 + i;          // 0..7 (16 rows each)
            const short* gA = A + (size_t)(row0 + chunk * 16 + ldr) * 2048 + ka0 + lko;
            const short* gB = W + (size_t)(col0 + chunk * 16 + ldr) * 2048 + kw0 + lko;
            async_copy16(gA, (char*)As + chunk * 1024);
            async_copy16(gB, (char*)Bs + chunk * 1024);
        }
        __syncthreads();
        bf16x8 af[4], bfr[4];
        #pragma unroll
        for (int mi = 0; mi < 4; ++mi)
            af[mi] = *(const bf16x8*)(As + (wm * 64 + mi * 16 + (lane & 15)) * 32 + (lane >> 4) * 8);
        #pragma unroll
        for (int ni = 0; ni < 4; ++ni)
            bfr[ni] = *(const bf16x8*)(Bs + (wn * 64 + ni * 16 + (lane & 15)) * 32 + (lane >> 4) * 8);
        #pragma unroll
        for (int mi = 0; mi < 4; ++mi)
            #pragma unroll
            for (int ni = 0; ni < 4; ++ni)
                acc[mi][ni] = __builtin_amdgcn_mfma_f32_16x16x32_bf16(af[mi], bfr[ni], acc[mi][ni], 0, 0, 0);
        __syncthreads();
    }

    // epilogue: scatter into q/k/v [B][H][N][HD]
    #pragma unroll
    for (int ni = 0; ni < 4; ++ni) {
        int gc = col0 + wn * 64 + ni * 16 + (lane & 15);   // 0..3071
        int tsel = gc >> 10;
        int h = (gc >> 6) & 15;
        int d = gc & 63;
        float* dst = (tsel == 0) ? qf : (tsel == 1) ? kf : vf;
        #pragma unroll
        for (int mi = 0; mi < 4; ++mi) {
            int gr0 = row0 + wm * 64 + mi * 16 + (lane >> 4) * 4;
            #pragma unroll
            for (int r = 0; r < 4; ++r) {
                int gr = gr0 + r;
                int b = gr >> 11, n = gr & 2047;
                dst[(((size_t)((b << 4) + h)) * NN + n) * HD64 + d] = acc[mi][ni][r];
            }
        }
    }
}

// Proj GEMM via bf16x3 MFMA + bias. A:[4096][2048] hi|lo, W:[1024][2048] hi|lo.
// 128(M)x64(N) tile, 4 waves each 32x64 (2x4 MFMA tiles).
__global__ __launch_bounds__(256) void proj_mfma_kernel(
    const short* __restrict__ A, const short* __restrict__ W,
    const float* __restrict__ bias, float* __restrict__ out)
{
    __shared__ short As[128 * 32];
    __shared__ short Bs[64 * 32];
    const int tid = threadIdx.x;
    const int lane = tid & 63;
    const int wave = tid >> 6;
    const int row0 = blockIdx.y * 128;
    const int col0 = blockIdx.x * 64;

    f32x4 acc[2][4];
    const f32x4 zero = {0.f, 0.f, 0.f, 0.f};
    #pragma unroll
    for (int i = 0; i < 2; ++i)
        #pragma unroll
        for (int j = 0; j < 4; ++j) acc[i][j] = zero;

    const int ldr = lane >> 2;
    const int lko = (lane & 3) * 8;

    for (int kt = 0; kt < 96; ++kt) {
        const int seg = kt >> 5;
        const int kk = (kt & 31) << 5;
        const int ka0 = kk + (seg == 2 ? 1024 : 0);
        const int kw0 = kk + (seg == 1 ? 1024 : 0);
        #pragma unroll
        for (int i = 0; i < 2; ++i) {
            const int chunk = wave * 2 + i;
            const short* gA = A + (size_t)(row0 + chunk * 16 + ldr) * 2048 + ka0 + lko;
            async_copy16(gA, (char*)As + chunk * 1024);
        }
        {
            const short* gB = W + (size_t)(col0 + wave * 16 + ldr) * 2048 + kw0 + lko;
            async_copy16(gB, (char*)Bs + wave * 1024);
        }
        __syncthreads();
        bf16x8 af[2], bfr[4];
        #pragma unroll
        for (int mi = 0; mi < 2; ++mi)
            af[mi] = *(const bf16x8*)(As + (wave * 32 + mi * 16 + (lane & 15)) * 32 + (lane >> 4) * 8);
        #pragma unroll
        for (int ni = 0; ni < 4; ++ni)
            bfr[ni] = *(const bf16x8*)(Bs + (ni * 16 + (lane & 15)) * 32 + (lane >> 4) * 8);
        #pragma unroll
        for (int mi = 0; mi < 2; ++mi)
            #pragma unroll
            for (int ni = 0; ni < 4; ++ni)
                acc[mi][ni] = __builtin_amdgcn_mfma_f32_16x16x32_bf16(af[mi], bfr[ni], acc[mi][ni], 0, 0, 0);
        __syncthreads();
    }

    #pragma unroll
    for (int ni = 0; ni < 4; ++ni) {
        int gc = col0 + ni * 16 + (lane & 15);
        float bv = bias[gc];
        #pragma unroll
        for (int mi = 0; mi < 2; ++mi) {
            int gr0 = row0 + wave * 32 + mi * 16 + (lane >> 4) * 4;
            #pragma unroll
            for (int r = 0; r < 4; ++r)
                out[(size_t)(gr0 + r) * 1024 + gc] = acc[mi][ni][r] + bv;
        }
    }
}

// ===========================================================================
// FALLBACK PATH (HW-proven round-2 fp32 GEMMs) — used if ws_size is too small
// ===========================================================================

__global__ __launch_bounds__(256) void qkv_gemm_fb(
    const float* __restrict__ x, const float* __restrict__ w,
    float* __restrict__ qf, float* __restrict__ kf, float* __restrict__ vf)
{
    __shared__ float As[64][33];
    __shared__ float Bs[64][33];
    const int tid = threadIdx.x;
    const int row0 = blockIdx.y * 64;
    const int col0 = blockIdx.x * 64;
    const int ty = tid >> 4, tx = tid & 15;

    float acc[4][4] = {};
    for (int k0 = 0; k0 < 1024; k0 += 32) {
        #pragma unroll
        for (int i = 0; i < 8; ++i) {
            int e = tid + i * 256;
            int r = e >> 5, c = e & 31;
            As[r][c] = x[(size_t)(row0 + r) * 1024 + k0 + c];
            Bs[r][c] = w[(size_t)(col0 + r) * 1024 + k0 + c];
        }
        __syncthreads();
        #pragma unroll
        for (int kk = 0; kk < 32; ++kk) {
            float a[4], b[4];
            #pragma unroll
            for (int i = 0; i < 4; ++i) a[i] = As[ty * 4 + i][kk];
            #pragma unroll
            for (int j = 0; j < 4; ++j) b[j] = Bs[tx * 4 + j][kk];
            #pragma unroll
            for (int i = 0; i < 4; ++i)
                #pragma unroll
                for (int j = 0; j < 4; ++j)
                    acc[i][j] += a[i] * b[j];
        }
        __syncthreads();
    }

    const int tsel = col0 >> 10;
    const int h    = (col0 & 1023) >> 6;
    float* dstbuf = (tsel == 0) ? qf : (tsel == 1) ? kf : vf;
    #pragma unroll
    for (int i = 0; i < 4; ++i) {
        int row = row0 + ty * 4 + i;
        int b   = row >> 11, n = row & 2047;
        size_t rb = ((size_t)(b * HH + h) * NN + n) * HD64;
        #pragma unroll
        for (int j = 0; j < 4; ++j)
            dstbuf[rb + tx * 4 + j] = acc[i][j];
    }
}

__global__ __launch_bounds__(256) void proj_gemm_fb(
    const float* __restrict__ attn, const float* __restrict__ w,
    const float* __restrict__ bias, float* __restrict__ out)
{
    __shared__ float As[64][33];
    __shared__ float Bs[64][33];
    const int tid = threadIdx.x;
    const int row0 = blockIdx.y * 64;
    const int col0 = blockIdx.x * 64;
    const int ty = tid >> 4, tx = tid & 15;

    float acc[4][4] = {};
    for (int k0 = 0; k0 < 1024; k0 += 32) {
        #pragma unroll
        for (int i = 0; i < 8; ++i) {
            int e = tid + i * 256;
            int r = e >> 5, c = e & 31;
            As[r][c] = attn[(size_t)(row0 + r) * 1024 + k0 + c];
            Bs[r][c] = w[(size_t)(col0 + r) * 1024 + k0 + c];
        }
        __syncthreads();
        #pragma unroll
        for (int kk = 0; kk < 32; ++kk) {
            float a[4], b[4];
            #pragma unroll
            for (int i = 0; i < 4; ++i) a[i] = As[ty * 4 + i][kk];
            #pragma unroll
            for (int j = 0; j < 4; ++j) b[j] = Bs[tx * 4 + j][kk];
            #pragma unroll
            for (int i = 0; i < 4; ++i)
                #pragma unroll
                for (int j = 0; j < 4; ++j)
                    acc[i][j] += a[i] * b[j];
        }
        __syncthreads();
    }

    #pragma unroll
    for (int j = 0; j < 4; ++j) {
        int col = col0 + tx * 4 + j;
        float bv = bias[col];
        #pragma unroll
        for (int i = 0; i < 4; ++i) {
            int row = row0 + ty * 4 + i;
            out[(size_t)row * 1024 + col] = acc[i][j] + bv;
        }
    }
}

// ===========================================================================
// SHARED KERNELS
// ===========================================================================

__global__ __launch_bounds__(256) void block_mean_kernel(
    const float* __restrict__ qf, const float* __restrict__ kf,
    float* __restrict__ qbf, float* __restrict__ kbf)
{
    int idx = blockIdx.x * 256 + threadIdx.x;   // 0..131071
    const float* src = (idx < 65536) ? qf : kf;
    float* dst       = (idx < 65536) ? qbf : kbf;
    int e = idx & 65535;
    int d = e & 63;
    int r = e >> 6;                              // bh*32 + m
    size_t base = (size_t)r * 4096 + d;
    float s = 0.f;
    #pragma unroll
    for (int i = 0; i < 64; ++i) s += src[base + (size_t)i * 64];
    dst[e] = s * (1.f / 64.f);
}

__global__ __launch_bounds__(128) void block_scores_kernel(
    const float* __restrict__ qbf, const float* __restrict__ kbf,
    unsigned int* __restrict__ maskbits)
{
    __shared__ float qs[32][64];
    __shared__ float ks[32][64];
    __shared__ float cb[32][32];
    const int bh = blockIdx.x;
    const int tid = threadIdx.x;

    #pragma unroll
    for (int i = 0; i < 16; ++i) {
        int e = tid + i * 128;
        qs[e >> 6][e & 63] = qbf[(size_t)bh * 2048 + e];
        ks[e >> 6][e & 63] = kbf[(size_t)bh * 2048 + e];
    }
    __syncthreads();

    #pragma unroll
    for (int i = 0; i < 8; ++i) {
        int idx = tid + i * 128;
        int r = idx >> 5, c = idx & 31;
        float s = 0.f;
        #pragma unroll
        for (int d = 0; d < 64; ++d) s += qs[r][d] * ks[c][d];
        cb[r][c] = s * SCALE_F;
    }
    __syncthreads();

    if (tid < 32) {
        float m1 = -INFINITY, m2 = -INFINITY;
        for (int n = 0; n < 32; ++n) {
            float v = cb[tid][n];
            if (v > m1) { m2 = m1; m1 = v; }
            else if (v > m2) { m2 = v; }
        }
        unsigned int bits = 1u << tid;
        for (int n = 0; n < 32; ++n)
            if (cb[tid][n] >= m2) bits |= 1u << n;
        maskbits[bh * 32 + tid] = bits;
    }
}

// ---------------------------------------------------------------------------
// Sparse block attention, v2: 256 threads per (bh,m) = 64 q-rows x 4 dim-groups.
// Thread (qr, dg) owns dims [dg*16, dg*16+16) of q and the output accumulator.
// Dot products reduce across the 4-lane group via shfl_xor; scores round-trip
// through padded sbuf (each wave owns its 16 q-rows -> no extra barriers).
// split_out=1: write bf16 hi|lo [4096][2048]; else fp32 [B][N][DIM].
// ---------------------------------------------------------------------------
__global__ __launch_bounds__(256) void sparse_attn_kernel(
    const float* __restrict__ qf, const float* __restrict__ kf,
    const float* __restrict__ vf, const unsigned int* __restrict__ maskbits,
    short* __restrict__ aout, float* __restrict__ attnf, int split_out)
{
    __shared__ float kbuf[64][64];   // [k-row][dim]
    __shared__ float vbuf[64][64];
    __shared__ float sbuf[64][65];   // [q-row][k], stride 65 -> conflict-free
    const int m  = blockIdx.x & 31;
    const int bh = blockIdx.x >> 5;
    const int b  = bh >> 4, h = bh & 15;
    const int t  = threadIdx.x;
    const int qr = t >> 2;           // 0..63  query row
    const int dg = t & 3;            // 0..3   dim group
    const int d0 = dg * 16;

    float qreg[16];
    {
        const float* qp = qf + ((size_t)bh * NN + m * 64 + qr) * HD64 + d0;
        #pragma unroll
        for (int j = 0; j < 16; j += 4) {
            float4 v = *(const float4*)(qp + j);
            qreg[j] = v.x; qreg[j+1] = v.y; qreg[j+2] = v.z; qreg[j+3] = v.w;
        }
    }

    const unsigned int mask = maskbits[bh * 32 + m];
    float macc = -INFINITY, lacc = 0.f;
    float oacc[16];
    #pragma unroll
    for (int j = 0; j < 16; ++j) oacc[j] = 0.f;

    for (int nb = 0; nb < 32; ++nb) {
        if (!((mask >> nb) & 1u)) continue;      // uniform across block
        __syncthreads();
        // Stage K/V blocks (each 16 KB contiguous) via global_load_lds width=16.
        {
            const float* gk = kf + ((size_t)bh * NN + nb * 64) * HD64;
            const float* gv = vf + ((size_t)bh * NN + nb * 64) * HD64;
            #pragma unroll
            for (int i = 0; i < 4; ++i) {
                async_copy16(gk + t * 4 + i * 1024, (char*)kbuf + t * 16 + i * 4096);
                async_copy16(gv + t * 4 + i * 1024, (char*)vbuf + t * 16 + i * 4096);
            }
        }
        __syncthreads();

        // Pass 1: scores for this thread's q-row (partial dot + 4-lane reduce)
        float bmax = -INFINITY;
        for (int kk = 0; kk < 64; ++kk) {
            float s = 0.f;
            #pragma unroll
            for (int j = 0; j < 16; ++j) s += qreg[j] * kbuf[kk][d0 + j];
            s += __shfl_xor(s, 1);
            s += __shfl_xor(s, 2);
            s *= SCALE_F;
            if (dg == 0) sbuf[qr][kk] = s;
            bmax = fmaxf(bmax, s);
        }

        float mnew  = fmaxf(macc, bmax);
        float alpha = expf(macc - mnew);         // macc=-inf -> 0, no NaN
        lacc *= alpha;
        #pragma unroll
        for (int j = 0; j < 16; ++j) oacc[j] *= alpha;

        // Pass 2: probabilities + PV accumulate on this thread's 16 dims
        for (int kk = 0; kk < 64; ++kk) {
            float p = expf(sbuf[qr][kk] - mnew);
            lacc += p;
            #pragma unroll
            for (int j = 0; j < 16; ++j) oacc[j] += p * vbuf[kk][d0 + j];
        }
        macc = mnew;
    }

    float inv = (lacc > 0.f) ? (1.f / lacc) : 0.f;
    if (split_out) {
        size_t orow = ((size_t)(b * NN + m * 64 + qr)) * 2048 + h * 64 + d0;
        #pragma unroll
        for (int j0 = 0; j0 < 16; j0 += 4) {
            float f0 = oacc[j0] * inv, f1 = oacc[j0 + 1] * inv,
                  f2 = oacc[j0 + 2] * inv, f3 = oacc[j0 + 3] * inv;
            unsigned short h0 = bf16_hi(f0), h1 = bf16_hi(f1), h2 = bf16_hi(f2), h3 = bf16_hi(f3);
            unsigned short l0 = bf16_hi(f0 - bf16_val(h0));
            unsigned short l1 = bf16_hi(f1 - bf16_val(h1));
            unsigned short l2 = bf16_hi(f2 - bf16_val(h2));
            unsigned short l3 = bf16_hi(f3 - bf16_val(h3));
            *(ushort4*)(aout + orow + j0)        = make_ushort4(h0, h1, h2, h3);
            *(ushort4*)(aout + orow + 1024 + j0) = make_ushort4(l0, l1, l2, l3);
        }
    } else {
        size_t orow = ((size_t)(b * NN + m * 64 + qr)) * DIMD + h * 64 + d0;
        #pragma unroll
        for (int j = 0; j < 16; ++j) attnf[orow + j] = oacc[j] * inv;
    }
}

// ---------------------------------------------------------------------------
extern "C" void kernel_launch(void* const* d_in, const int* in_sizes, int n_in,
                              void* d_out, int out_size, void* d_ws, size_t ws_size,
                              hipStream_t stream)
{
    const float* x      = (const float*)d_in[0];
    const float* qkv_w  = (const float*)d_in[1];
    const float* proj_w = (const float*)d_in[2];
    const float* proj_b = (const float*)d_in[3];
    float* out = (float*)d_out;

    // Common carve (fp32): q,k,v 3x 4194304 + qb,kb 2x 65536 + mask
    float* qf  = (float*)d_ws;
    float* kf  = qf + 4194304;
    float* vf  = kf + 4194304;
    float* qbf = vf + 4194304;
    float* kbf = qbf + 65536;
    unsigned int* maskb = (unsigned int*)(kbf + 65536);

    // Fast-path extra: Axs 4096*2048 bf16 (x split; reused for attn split),
    // Wqs 3072*2048 bf16 (qkv_w split; reused for proj_w split)
    short* Axs = (short*)(maskb + 1024);
    short* Wqs = Axs + (size_t)4096 * 2048;
    const size_t need_fast = (size_t)((char*)(Wqs + (size_t)3072 * 2048) - (char*)d_ws);

    if (ws_size >= need_fast) {
        split_bf16_kernel<<<4096, 256, 0, stream>>>(x, Axs, 1048576);
        split_bf16_kernel<<<3072, 256, 0, stream>>>(qkv_w, Wqs, 786432);
        qkv_mfma_kernel<<<dim3(24, 32), 256, 0, stream>>>(Axs, Wqs, qf, kf, vf);
        block_mean_kernel<<<512, 256, 0, stream>>>(qf, kf, qbf, kbf);
        block_scores_kernel<<<32, 128, 0, stream>>>(qbf, kbf, maskb);
        split_bf16_kernel<<<1024, 256, 0, stream>>>(proj_w, Wqs, 262144);
        sparse_attn_kernel<<<1024, 256, 0, stream>>>(qf, kf, vf, maskb, Axs, (float*)nullptr, 1);
        proj_mfma_kernel<<<dim3(16, 32), 256, 0, stream>>>(Axs, Wqs, proj_b, out);
    } else {
        // Round-2 proven path: attnf fp32 reuses the fast-path split region
        float* attnf = (float*)(maskb + 1024);
        qkv_gemm_fb<<<dim3(48, 64), 256, 0, stream>>>(x, qkv_w, qf, kf, vf);
        block_mean_kernel<<<512, 256, 0, stream>>>(qf, kf, qbf, kbf);
        block_scores_kernel<<<32, 128, 0, stream>>>(qbf, kbf, maskb);
        sparse_attn_kernel<<<1024, 256, 0, stream>>>(qf, kf, vf, maskb, (short*)nullptr, attnf, 0);
        proj_gemm_fb<<<dim3(16, 64), 256, 0, stream>>>(attnf, proj_w, proj_b, out);
    }
}

// Round 6
// 299.716 us; speedup vs baseline: 3.5494x; 1.2831x over previous
//
#include <hip/hip_runtime.h>
#include <hip/hip_bf16.h>

// Problem constants (B=2, N=2048, DIM=1024, H=16, HD=64, BS=64, M=32)
#define BB 2
#define NN 2048
#define DIMD 1024
#define HH 16
#define HD64 64
#define MB 32
#define SCALE_F 0.125f   // HD^-0.5

typedef __attribute__((ext_vector_type(8))) short bf16x8;
typedef __attribute__((ext_vector_type(4))) float f32x4;
typedef _Float16 f16;
typedef __attribute__((ext_vector_type(8))) _Float16 f16x8;

#define LSTR 72   // padded LDS row stride (f16 elems): 144B rows, 16B-aligned, 4-way-min frag reads

__device__ __forceinline__ unsigned short bf16_hi(float f) {
    return __builtin_bit_cast(unsigned short, __float2bfloat16(f));
}
__device__ __forceinline__ float bf16_val(unsigned short u) {
    return __bfloat162float(__builtin_bit_cast(__hip_bfloat16, u));
}
__device__ __forceinline__ void async_copy16(const void* g, void* l) {
    __builtin_amdgcn_global_load_lds((const __attribute__((address_space(1))) void*)g,
                                     (__attribute__((address_space(3))) void*)l, 16, 0, 0);
}

// ===========================================================================
// FAST PATH
// ===========================================================================

// Split fp32 [rows][1024] -> bf16 hi|lo [rows][2048] (hi at col, lo at col+1024)
__global__ __launch_bounds__(256) void split_bf16_kernel(
    const float* __restrict__ src, short* __restrict__ dst, int total4)
{
    int idx = blockIdx.x * 256 + threadIdx.x;
    if (idx >= total4) return;
    int e = idx * 4;
    int r = e >> 10, c = e & 1023;
    float4 v = *(const float4*)(src + e);
    unsigned short h0 = bf16_hi(v.x), h1 = bf16_hi(v.y), h2 = bf16_hi(v.z), h3 = bf16_hi(v.w);
    unsigned short l0 = bf16_hi(v.x - bf16_val(h0));
    unsigned short l1 = bf16_hi(v.y - bf16_val(h1));
    unsigned short l2 = bf16_hi(v.z - bf16_val(h2));
    unsigned short l3 = bf16_hi(v.w - bf16_val(h3));
    size_t base = (size_t)r * 2048 + c;
    *(ushort4*)(dst + base)        = make_ushort4(h0, h1, h2, h3);
    *(ushort4*)(dst + base + 1024) = make_ushort4(l0, l1, l2, l3);
}

// QKV GEMM via bf16x3 MFMA. Pre-scales q by SCALE_F (exact, x2^-3) so the
// attention and coarse-score paths need no separate scale.
__global__ __launch_bounds__(256) void qkv_mfma_kernel(
    const short* __restrict__ A, const short* __restrict__ W,
    float* __restrict__ qf, float* __restrict__ kf, float* __restrict__ vf)
{
    __shared__ short As[128 * 32];
    __shared__ short Bs[128 * 32];
    const int tid = threadIdx.x;
    const int lane = tid & 63;
    const int wave = tid >> 6;
    const int row0 = blockIdx.y * 128;
    const int col0 = blockIdx.x * 128;
    const int wm = wave & 1, wn = wave >> 1;

    f32x4 acc[4][4];
    const f32x4 zero = {0.f, 0.f, 0.f, 0.f};
    #pragma unroll
    for (int i = 0; i < 4; ++i)
        #pragma unroll
        for (int j = 0; j < 4; ++j) acc[i][j] = zero;

    const int ldr = lane >> 2;
    const int lko = (lane & 3) * 8;

    for (int kt = 0; kt < 96; ++kt) {
        const int seg = kt >> 5;
        const int kk = (kt & 31) << 5;
        const int ka0 = kk + (seg == 2 ? 1024 : 0);
        const int kw0 = kk + (seg == 1 ? 1024 : 0);
        #pragma unroll
        for (int i = 0; i < 2; ++i) {
            const int chunk = wave * 2 + i;
            const short* gA = A + (size_t)(row0 + chunk * 16 + ldr) * 2048 + ka0 + lko;
            const short* gB = W + (size_t)(col0 + chunk * 16 + ldr) * 2048 + kw0 + lko;
            async_copy16(gA, (char*)As + chunk * 1024);
            async_copy16(gB, (char*)Bs + chunk * 1024);
        }
        __syncthreads();
        bf16x8 af[4], bfr[4];
        #pragma unroll
        for (int mi = 0; mi < 4; ++mi)
            af[mi] = *(const bf16x8*)(As + (wm * 64 + mi * 16 + (lane & 15)) * 32 + (lane >> 4) * 8);
        #pragma unroll
        for (int ni = 0; ni < 4; ++ni)
            bfr[ni] = *(const bf16x8*)(Bs + (wn * 64 + ni * 16 + (lane & 15)) * 32 + (lane >> 4) * 8);
        #pragma unroll
        for (int mi = 0; mi < 4; ++mi)
            #pragma unroll
            for (int ni = 0; ni < 4; ++ni)
                acc[mi][ni] = __builtin_amdgcn_mfma_f32_16x16x32_bf16(af[mi], bfr[ni], acc[mi][ni], 0, 0, 0);
        __syncthreads();
    }

    #pragma unroll
    for (int ni = 0; ni < 4; ++ni) {
        int gc = col0 + wn * 64 + ni * 16 + (lane & 15);
        int tsel = gc >> 10;
        int h = (gc >> 6) & 15;
        int d = gc & 63;
        float* dst = (tsel == 0) ? qf : (tsel == 1) ? kf : vf;
        float sc = (tsel == 0) ? SCALE_F : 1.0f;
        #pragma unroll
        for (int mi = 0; mi < 4; ++mi) {
            int gr0 = row0 + wm * 64 + mi * 16 + (lane >> 4) * 4;
            #pragma unroll
            for (int r = 0; r < 4; ++r) {
                int gr = gr0 + r;
                int b = gr >> 11, n = gr & 2047;
                dst[(((size_t)((b << 4) + h)) * NN + n) * HD64 + d] = acc[mi][ni][r] * sc;
            }
        }
    }
}

// Proj GEMM via bf16x3 MFMA + bias.
__global__ __launch_bounds__(256) void proj_mfma_kernel(
    const short* __restrict__ A, const short* __restrict__ W,
    const float* __restrict__ bias, float* __restrict__ out)
{
    __shared__ short As[128 * 32];
    __shared__ short Bs[64 * 32];
    const int tid = threadIdx.x;
    const int lane = tid & 63;
    const int wave = tid >> 6;
    const int row0 = blockIdx.y * 128;
    const int col0 = blockIdx.x * 64;

    f32x4 acc[2][4];
    const f32x4 zero = {0.f, 0.f, 0.f, 0.f};
    #pragma unroll
    for (int i = 0; i < 2; ++i)
        #pragma unroll
        for (int j = 0; j < 4; ++j) acc[i][j] = zero;

    const int ldr = lane >> 2;
    const int lko = (lane & 3) * 8;

    for (int kt = 0; kt < 96; ++kt) {
        const int seg = kt >> 5;
        const int kk = (kt & 31) << 5;
        const int ka0 = kk + (seg == 2 ? 1024 : 0);
        const int kw0 = kk + (seg == 1 ? 1024 : 0);
        #pragma unroll
        for (int i = 0; i < 2; ++i) {
            const int chunk = wave * 2 + i;
            const short* gA = A + (size_t)(row0 + chunk * 16 + ldr) * 2048 + ka0 + lko;
            async_copy16(gA, (char*)As + chunk * 1024);
        }
        {
            const short* gB = W + (size_t)(col0 + wave * 16 + ldr) * 2048 + kw0 + lko;
            async_copy16(gB, (char*)Bs + wave * 1024);
        }
        __syncthreads();
        bf16x8 af[2], bfr[4];
        #pragma unroll
        for (int mi = 0; mi < 2; ++mi)
            af[mi] = *(const bf16x8*)(As + (wave * 32 + mi * 16 + (lane & 15)) * 32 + (lane >> 4) * 8);
        #pragma unroll
        for (int ni = 0; ni < 4; ++ni)
            bfr[ni] = *(const bf16x8*)(Bs + (ni * 16 + (lane & 15)) * 32 + (lane >> 4) * 8);
        #pragma unroll
        for (int mi = 0; mi < 2; ++mi)
            #pragma unroll
            for (int ni = 0; ni < 4; ++ni)
                acc[mi][ni] = __builtin_amdgcn_mfma_f32_16x16x32_bf16(af[mi], bfr[ni], acc[mi][ni], 0, 0, 0);
        __syncthreads();
    }

    #pragma unroll
    for (int ni = 0; ni < 4; ++ni) {
        int gc = col0 + ni * 16 + (lane & 15);
        float bv = bias[gc];
        #pragma unroll
        for (int mi = 0; mi < 2; ++mi) {
            int gr0 = row0 + wave * 32 + mi * 16 + (lane >> 4) * 4;
            #pragma unroll
            for (int r = 0; r < 4; ++r)
                out[(size_t)(gr0 + r) * 1024 + gc] = acc[mi][ni][r] + bv;
        }
    }
}

// ---------------------------------------------------------------------------
// Sparse block attention on MFMA. One block per (bh,m), 256 threads = 4 waves.
// Wave w owns query rows [w*16, w*16+16). QK^T: f16x3 emulation; PV: f16.
// q arrives PRE-SCALED by SCALE_F. Output: bf16 hi|lo split [4096][2048].
// ---------------------------------------------------------------------------
__global__ __launch_bounds__(256) void sparse_attn_mfma_kernel(
    const float* __restrict__ qf, const float* __restrict__ kf,
    const float* __restrict__ vf, const unsigned int* __restrict__ maskbits,
    short* __restrict__ aout)
{
    __shared__ f16 Qh[64 * LSTR], Ql[64 * LSTR];
    __shared__ f16 Kh[64 * LSTR], Kl[64 * LSTR];
    __shared__ f16 Vt[64 * LSTR];            // Vt[d][kk]
    __shared__ f16 Pb[64 * LSTR];            // P[q][kk], wave-private rows

    const int m  = blockIdx.x & 31;
    const int bh = blockIdx.x >> 5;
    const int b  = bh >> 4, h = bh & 15;
    const int tid = threadIdx.x;
    const int lane = tid & 63;
    const int wave = tid >> 6;
    const f32x4 zero = {0.f, 0.f, 0.f, 0.f};

    // ---- stage Q (once): thread t -> row t>>2, cols (t&3)*16..+16, split f16
    {
        const int r = tid >> 2, c0 = (tid & 3) * 16;
        const float* src = qf + ((size_t)bh * NN + m * 64 + r) * HD64 + c0;
        #pragma unroll
        for (int j = 0; j < 16; j += 8) {
            f16x8 hv, lv;
            #pragma unroll
            for (int u = 0; u < 8; u += 4) {
                float4 v4 = *(const float4*)(src + j + u);
                float vv[4] = {v4.x, v4.y, v4.z, v4.w};
                #pragma unroll
                for (int w = 0; w < 4; ++w) {
                    f16 hh = (f16)vv[w];
                    hv[u + w] = hh;
                    lv[u + w] = (f16)(vv[w] - (float)hh);
                }
            }
            *(f16x8*)(Qh + r * LSTR + c0 + j) = hv;
            *(f16x8*)(Ql + r * LSTR + c0 + j) = lv;
        }
    }
    __syncthreads();

    const unsigned int mask = maskbits[bh * 32 + m];
    f32x4 s_acc[4], o_acc[4];
    float macc[4], lacc[4];
    #pragma unroll
    for (int r = 0; r < 4; ++r) { macc[r] = -INFINITY; lacc[r] = 0.f; }
    #pragma unroll
    for (int t = 0; t < 4; ++t) o_acc[t] = zero;

    const int arow = wave * 16 + (lane & 15);     // A-frag row (q)
    const int kofs = (lane >> 4) * 8;             // k offset within 32-chunk

    for (int nb = 0; nb < 32; ++nb) {
        if (!((mask >> nb) & 1u)) continue;       // uniform across block
        __syncthreads();                          // protect K/V LDS from prior reads

        // stage K split (rows kk, dims d): thread -> row t>>2, cols (t&3)*16
        {
            const int r = tid >> 2, c0 = (tid & 3) * 16;
            const float* srck = kf + ((size_t)bh * NN + nb * 64 + r) * HD64 + c0;
            #pragma unroll
            for (int j = 0; j < 16; j += 8) {
                f16x8 hv, lv;
                #pragma unroll
                for (int u = 0; u < 8; u += 4) {
                    float4 v4 = *(const float4*)(srck + j + u);
                    float vv[4] = {v4.x, v4.y, v4.z, v4.w};
                    #pragma unroll
                    for (int w = 0; w < 4; ++w) {
                        f16 hh = (f16)vv[w];
                        hv[u + w] = hh;
                        lv[u + w] = (f16)(vv[w] - (float)hh);
                    }
                }
                *(f16x8*)(Kh + r * LSTR + c0 + j) = hv;
                *(f16x8*)(Kl + r * LSTR + c0 + j) = lv;
            }
            // stage V transposed: thread -> Vt row d=t>>2, kk (t&3)*16..+16
            const int d = tid >> 2, kk0 = (tid & 3) * 16;
            const float* srcv = vf + ((size_t)bh * NN + nb * 64 + kk0) * HD64 + d;
            #pragma unroll
            for (int j = 0; j < 16; j += 8) {
                f16x8 tv;
                #pragma unroll
                for (int u = 0; u < 8; ++u) tv[u] = (f16)srcv[(size_t)(j + u) * 64];
                *(f16x8*)(Vt + d * LSTR + kk0 + j) = tv;
            }
        }
        __syncthreads();

        // ---- QK^T: 3 emulation terms x 2 k-chunks x 4 col-tiles
        #pragma unroll
        for (int t = 0; t < 4; ++t) s_acc[t] = zero;
        #pragma unroll
        for (int c = 0; c < 2; ++c) {
            f16x8 ah = *(const f16x8*)(Qh + arow * LSTR + c * 32 + kofs);
            f16x8 al = *(const f16x8*)(Ql + arow * LSTR + c * 32 + kofs);
            #pragma unroll
            for (int t = 0; t < 4; ++t) {
                f16x8 bh_ = *(const f16x8*)(Kh + (t * 16 + (lane & 15)) * LSTR + c * 32 + kofs);
                f16x8 bl_ = *(const f16x8*)(Kl + (t * 16 + (lane & 15)) * LSTR + c * 32 + kofs);
                s_acc[t] = __builtin_amdgcn_mfma_f32_16x16x32_f16(ah, bh_, s_acc[t], 0, 0, 0);
                s_acc[t] = __builtin_amdgcn_mfma_f32_16x16x32_f16(ah, bl_, s_acc[t], 0, 0, 0);
                s_acc[t] = __builtin_amdgcn_mfma_f32_16x16x32_f16(al, bh_, s_acc[t], 0, 0, 0);
            }
        }

        // ---- online softmax (rows = wave*16 + (lane>>4)*4 + r)
        float alpha[4], psum[4];
        #pragma unroll
        for (int r = 0; r < 4; ++r) {
            float v0 = fmaxf(fmaxf(s_acc[0][r], s_acc[1][r]), fmaxf(s_acc[2][r], s_acc[3][r]));
            #pragma unroll
            for (int off = 1; off < 16; off <<= 1)
                v0 = fmaxf(v0, __shfl_xor(v0, off));
            float mnew = fmaxf(macc[r], v0);
            alpha[r] = expf(macc[r] - mnew);      // -inf start -> 0, no NaN
            macc[r] = mnew;
            psum[r] = 0.f;
        }
        #pragma unroll
        for (int t = 0; t < 4; ++t) {
            #pragma unroll
            for (int r = 0; r < 4; ++r) {
                float p = expf(s_acc[t][r] - macc[r]);
                psum[r] += p;
                Pb[(wave * 16 + (lane >> 4) * 4 + r) * LSTR + t * 16 + (lane & 15)] = (f16)p;
            }
        }
        #pragma unroll
        for (int r = 0; r < 4; ++r) {
            float v0 = psum[r];
            #pragma unroll
            for (int off = 1; off < 16; off <<= 1) v0 += __shfl_xor(v0, off);
            lacc[r] = lacc[r] * alpha[r] + v0;
            #pragma unroll
            for (int t = 0; t < 4; ++t) o_acc[t][r] *= alpha[r];
        }
        __syncthreads();   // order Pb writes before frag reads (cheap insurance)

        // ---- PV: O[q][d] += P[q][kk] * Vt[d][kk]
        #pragma unroll
        for (int c = 0; c < 2; ++c) {
            f16x8 af = *(const f16x8*)(Pb + arow * LSTR + c * 32 + kofs);
            #pragma unroll
            for (int t = 0; t < 4; ++t) {
                f16x8 bf = *(const f16x8*)(Vt + (t * 16 + (lane & 15)) * LSTR + c * 32 + kofs);
                o_acc[t] = __builtin_amdgcn_mfma_f32_16x16x32_f16(af, bf, o_acc[t], 0, 0, 0);
            }
        }
    }

    // ---- epilogue: normalize, split bf16 hi|lo, scatter
    float inv[4];
    #pragma unroll
    for (int r = 0; r < 4; ++r) inv[r] = (lacc[r] > 0.f) ? (1.f / lacc[r]) : 0.f;
    #pragma unroll
    for (int t = 0; t < 4; ++t) {
        int gc = h * 64 + t * 16 + (lane & 15);
        #pragma unroll
        for (int r = 0; r < 4; ++r) {
            int grow = b * NN + m * 64 + wave * 16 + (lane >> 4) * 4 + r;
            float v = o_acc[t][r] * inv[r];
            unsigned short hh = bf16_hi(v);
            unsigned short ll = bf16_hi(v - bf16_val(hh));
            aout[(size_t)grow * 2048 + gc] = (short)hh;
            aout[(size_t)grow * 2048 + 1024 + gc] = (short)ll;
        }
    }
}

// ===========================================================================
// SHARED / FALLBACK KERNELS
// ===========================================================================

__global__ __launch_bounds__(256) void block_mean_kernel(
    const float* __restrict__ qf, const float* __restrict__ kf,
    float* __restrict__ qbf, float* __restrict__ kbf)
{
    int idx = blockIdx.x * 256 + threadIdx.x;
    const float* src = (idx < 65536) ? qf : kf;
    float* dst       = (idx < 65536) ? qbf : kbf;
    int e = idx & 65535;
    int d = e & 63;
    int r = e >> 6;
    size_t base = (size_t)r * 4096 + d;
    float s = 0.f;
    #pragma unroll
    for (int i = 0; i < 64; ++i) s += src[base + (size_t)i * 64];
    dst[e] = s * (1.f / 64.f);
}

// scale: fast path passes 1.0 (q pre-scaled); fallback passes SCALE_F.
__global__ __launch_bounds__(128) void block_scores_kernel(
    const float* __restrict__ qbf, const float* __restrict__ kbf,
    unsigned int* __restrict__ maskbits, float scale)
{
    __shared__ float qs[32][64];
    __shared__ float ks[32][64];
    __shared__ float cb[32][32];
    const int bh = blockIdx.x;
    const int tid = threadIdx.x;

    #pragma unroll
    for (int i = 0; i < 16; ++i) {
        int e = tid + i * 128;
        qs[e >> 6][e & 63] = qbf[(size_t)bh * 2048 + e];
        ks[e >> 6][e & 63] = kbf[(size_t)bh * 2048 + e];
    }
    __syncthreads();

    #pragma unroll
    for (int i = 0; i < 8; ++i) {
        int idx = tid + i * 128;
        int r = idx >> 5, c = idx & 31;
        float s = 0.f;
        #pragma unroll
        for (int d = 0; d < 64; ++d) s += qs[r][d] * ks[c][d];
        cb[r][c] = s * scale;
    }
    __syncthreads();

    if (tid < 32) {
        float m1 = -INFINITY, m2 = -INFINITY;
        for (int n = 0; n < 32; ++n) {
            float v = cb[tid][n];
            if (v > m1) { m2 = m1; m1 = v; }
            else if (v > m2) { m2 = v; }
        }
        unsigned int bits = 1u << tid;
        for (int n = 0; n < 32; ++n)
            if (cb[tid][n] >= m2) bits |= 1u << n;
        maskbits[bh * 32 + tid] = bits;
    }
}

__global__ __launch_bounds__(256) void qkv_gemm_fb(
    const float* __restrict__ x, const float* __restrict__ w,
    float* __restrict__ qf, float* __restrict__ kf, float* __restrict__ vf)
{
    __shared__ float As[64][33];
    __shared__ float Bs[64][33];
    const int tid = threadIdx.x;
    const int row0 = blockIdx.y * 64;
    const int col0 = blockIdx.x * 64;
    const int ty = tid >> 4, tx = tid & 15;

    float acc[4][4] = {};
    for (int k0 = 0; k0 < 1024; k0 += 32) {
        #pragma unroll
        for (int i = 0; i < 8; ++i) {
            int e = tid + i * 256;
            int r = e >> 5, c = e & 31;
            As[r][c] = x[(size_t)(row0 + r) * 1024 + k0 + c];
            Bs[r][c] = w[(size_t)(col0 + r) * 1024 + k0 + c];
        }
        __syncthreads();
        #pragma unroll
        for (int kk = 0; kk < 32; ++kk) {
            float a[4], b[4];
            #pragma unroll
            for (int i = 0; i < 4; ++i) a[i] = As[ty * 4 + i][kk];
            #pragma unroll
            for (int j = 0; j < 4; ++j) b[j] = Bs[tx * 4 + j][kk];
            #pragma unroll
            for (int i = 0; i < 4; ++i)
                #pragma unroll
                for (int j = 0; j < 4; ++j)
                    acc[i][j] += a[i] * b[j];
        }
        __syncthreads();
    }

    const int tsel = col0 >> 10;
    const int h    = (col0 & 1023) >> 6;
    float* dstbuf = (tsel == 0) ? qf : (tsel == 1) ? kf : vf;
    #pragma unroll
    for (int i = 0; i < 4; ++i) {
        int row = row0 + ty * 4 + i;
        int b   = row >> 11, n = row & 2047;
        size_t rb = ((size_t)(b * HH + h) * NN + n) * HD64;
        #pragma unroll
        for (int j = 0; j < 4; ++j)
            dstbuf[rb + tx * 4 + j] = acc[i][j];
    }
}

__global__ __launch_bounds__(256) void proj_gemm_fb(
    const float* __restrict__ attn, const float* __restrict__ w,
    const float* __restrict__ bias, float* __restrict__ out)
{
    __shared__ float As[64][33];
    __shared__ float Bs[64][33];
    const int tid = threadIdx.x;
    const int row0 = blockIdx.y * 64;
    const int col0 = blockIdx.x * 64;
    const int ty = tid >> 4, tx = tid & 15;

    float acc[4][4] = {};
    for (int k0 = 0; k0 < 1024; k0 += 32) {
        #pragma unroll
        for (int i = 0; i < 8; ++i) {
            int e = tid + i * 256;
            int r = e >> 5, c = e & 31;
            As[r][c] = attn[(size_t)(row0 + r) * 1024 + k0 + c];
            Bs[r][c] = w[(size_t)(col0 + r) * 1024 + k0 + c];
        }
        __syncthreads();
        #pragma unroll
        for (int kk = 0; kk < 32; ++kk) {
            float a[4], b[4];
            #pragma unroll
            for (int i = 0; i < 4; ++i) a[i] = As[ty * 4 + i][kk];
            #pragma unroll
            for (int j = 0; j < 4; ++j) b[j] = Bs[tx * 4 + j][kk];
            #pragma unroll
            for (int i = 0; i < 4; ++i)
                #pragma unroll
                for (int j = 0; j < 4; ++j)
                    acc[i][j] += a[i] * b[j];
        }
        __syncthreads();
    }

    #pragma unroll
    for (int j = 0; j < 4; ++j) {
        int col = col0 + tx * 4 + j;
        float bv = bias[col];
        #pragma unroll
        for (int i = 0; i < 4; ++i) {
            int row = row0 + ty * 4 + i;
            out[(size_t)row * 1024 + col] = acc[i][j] + bv;
        }
    }
}

// Fallback scalar attention (q NOT pre-scaled), fp32 output [B][N][DIM].
__global__ __launch_bounds__(256) void sparse_attn_fb(
    const float* __restrict__ qf, const float* __restrict__ kf,
    const float* __restrict__ vf, const unsigned int* __restrict__ maskbits,
    float* __restrict__ attnf)
{
    __shared__ float kbuf[64][64];
    __shared__ float vbuf[64][64];
    __shared__ float sbuf[64][65];
    const int m  = blockIdx.x & 31;
    const int bh = blockIdx.x >> 5;
    const int b  = bh >> 4, h = bh & 15;
    const int t  = threadIdx.x;
    const int qr = t >> 2;
    const int dg = t & 3;
    const int d0 = dg * 16;

    float qreg[16];
    {
        const float* qp = qf + ((size_t)bh * NN + m * 64 + qr) * HD64 + d0;
        #pragma unroll
        for (int j = 0; j < 16; j += 4) {
            float4 v = *(const float4*)(qp + j);
            qreg[j] = v.x; qreg[j+1] = v.y; qreg[j+2] = v.z; qreg[j+3] = v.w;
        }
    }

    const unsigned int mask = maskbits[bh * 32 + m];
    float macc = -INFINITY, lacc = 0.f;
    float oacc[16];
    #pragma unroll
    for (int j = 0; j < 16; ++j) oacc[j] = 0.f;

    for (int nb = 0; nb < 32; ++nb) {
        if (!((mask >> nb) & 1u)) continue;
        __syncthreads();
        {
            const float* gk = kf + ((size_t)bh * NN + nb * 64) * HD64;
            const float* gv = vf + ((size_t)bh * NN + nb * 64) * HD64;
            #pragma unroll
            for (int i = 0; i < 4; ++i) {
                async_copy16(gk + t * 4 + i * 1024, (char*)kbuf + t * 16 + i * 4096);
                async_copy16(gv + t * 4 + i * 1024, (char*)vbuf + t * 16 + i * 4096);
            }
        }
        __syncthreads();

        float bmax = -INFINITY;
        for (int kk = 0; kk < 64; ++kk) {
            float s = 0.f;
            #pragma unroll
            for (int j = 0; j < 16; ++j) s += qreg[j] * kbuf[kk][d0 + j];
            s += __shfl_xor(s, 1);
            s += __shfl_xor(s, 2);
            s *= SCALE_F;
            if (dg == 0) sbuf[qr][kk] = s;
            bmax = fmaxf(bmax, s);
        }
        float mnew  = fmaxf(macc, bmax);
        float alpha = expf(macc - mnew);
        lacc *= alpha;
        #pragma unroll
        for (int j = 0; j < 16; ++j) oacc[j] *= alpha;
        for (int kk = 0; kk < 64; ++kk) {
            float p = expf(sbuf[qr][kk] - mnew);
            lacc += p;
            #pragma unroll
            for (int j = 0; j < 16; ++j) oacc[j] += p * vbuf[kk][d0 + j];
        }
        macc = mnew;
    }

    float inv = (lacc > 0.f) ? (1.f / lacc) : 0.f;
    size_t orow = ((size_t)(b * NN + m * 64 + qr)) * DIMD + h * 64 + d0;
    #pragma unroll
    for (int j = 0; j < 16; ++j) attnf[orow + j] = oacc[j] * inv;
}

// ---------------------------------------------------------------------------
extern "C" void kernel_launch(void* const* d_in, const int* in_sizes, int n_in,
                              void* d_out, int out_size, void* d_ws, size_t ws_size,
                              hipStream_t stream)
{
    const float* x      = (const float*)d_in[0];
    const float* qkv_w  = (const float*)d_in[1];
    const float* proj_w = (const float*)d_in[2];
    const float* proj_b = (const float*)d_in[3];
    float* out = (float*)d_out;

    float* qf  = (float*)d_ws;
    float* kf  = qf + 4194304;
    float* vf  = kf + 4194304;
    float* qbf = vf + 4194304;
    float* kbf = qbf + 65536;
    unsigned int* maskb = (unsigned int*)(kbf + 65536);

    short* Axs = (short*)(maskb + 1024);
    short* Wqs = Axs + (size_t)4096 * 2048;
    const size_t need_fast = (size_t)((char*)(Wqs + (size_t)3072 * 2048) - (char*)d_ws);

    if (ws_size >= need_fast) {
        split_bf16_kernel<<<4096, 256, 0, stream>>>(x, Axs, 1048576);
        split_bf16_kernel<<<3072, 256, 0, stream>>>(qkv_w, Wqs, 786432);
        qkv_mfma_kernel<<<dim3(24, 32), 256, 0, stream>>>(Axs, Wqs, qf, kf, vf);
        block_mean_kernel<<<512, 256, 0, stream>>>(qf, kf, qbf, kbf);
        block_scores_kernel<<<32, 128, 0, stream>>>(qbf, kbf, maskb, 1.0f);
        split_bf16_kernel<<<1024, 256, 0, stream>>>(proj_w, Wqs, 262144);
        sparse_attn_mfma_kernel<<<1024, 256, 0, stream>>>(qf, kf, vf, maskb, Axs);
        proj_mfma_kernel<<<dim3(16, 32), 256, 0, stream>>>(Axs, Wqs, proj_b, out);
    } else {
        float* attnf = (float*)(maskb + 1024);
        qkv_gemm_fb<<<dim3(48, 64), 256, 0, stream>>>(x, qkv_w, qf, kf, vf);
        block_mean_kernel<<<512, 256, 0, stream>>>(qf, kf, qbf, kbf);
        block_scores_kernel<<<32, 128, 0, stream>>>(qbf, kbf, maskb, SCALE_F);
        sparse_attn_fb<<<1024, 256, 0, stream>>>(qf, kf, vf, maskb, attnf);
        proj_gemm_fb<<<dim3(16, 64), 256, 0, stream>>>(attnf, proj_w, proj_b, out);
    }
}